// Round 4
// baseline (90.472 us; speedup 1.0000x reference)
//
#include <hip/hip_runtime.h>
#include <math.h>

#define TPB 256
#define IB 64
#define EPSF 1e-15f

// Three-kernel structure:
//  prep    : per-element scalars  R = (g1+log y)/(h*sqrt(2 ln 2)), d, L = exp(g2-g1),
//            plus per-block partial sums of L (for the 0.5*sum(L) Phi term).
//  pair    : O(n^2) loop with NO LDS and NO barriers. i-data is read with
//            wave-uniform addresses from const __restrict__ arrays -> compiler
//            scalarizes to s_load (K$), leaving a pure VALU/trans loop whose
//            only vector-memory op is the final P store. This removes the
//            ds_read latency (~120cyc) from every k-iter's dependent chain,
//            which R1-R3 evidence identified as the 39us bottleneck.
//  finalize: column reduction + log terms; adds 0.5*sum(L) once.
//
// Math identical to the proven kernel: exp(-0.5*((Ri-Rj)/h)^2) = exp2(-dr^2)
// in scaled units; Phi via A&S 7.1.25 3-term erfc reusing the same exp2
// (|eps|<=2.5e-5); sign applied by XOR on (0.5-u) — exactly equal to
// copysign(L,dr)*(0.5-u) since L>0 and sign-flip of an fma operand is exact.

__global__ __launch_bounds__(TPB) void prep_kernel(
    const float* __restrict__ m_z, const float* __restrict__ y,
    const float* __restrict__ delta,
    float* __restrict__ Rarr, float* __restrict__ Darr, float* __restrict__ Larr,
    float* __restrict__ LP, float inv_hk) {
    const int i = blockIdx.x * TPB + threadIdx.x;
    const float2 g = ((const float2*)m_z)[i];
    const float L = __expf(g.y - g.x);
    Rarr[i] = (g.x + __logf(y[i])) * inv_hk;
    Darr[i] = delta[i];
    Larr[i] = L;
    float s = L;                         // block partial sum of L
    for (int o = 32; o > 0; o >>= 1) s += __shfl_down(s, o, 64);
    __shared__ float wsum[TPB / 64];
    if ((threadIdx.x & 63) == 0) wsum[threadIdx.x >> 6] = s;
    __syncthreads();
    if (threadIdx.x == 0) {
        float t = 0.0f;
        for (int w = 0; w < TPB / 64; ++w) t += wsum[w];
        LP[blockIdx.x] = t;
    }
}

__global__ __launch_bounds__(TPB, 8) void pair_kernel(
    const float* __restrict__ Rarr, const float* __restrict__ Darr,
    const float* __restrict__ Larr, float2* __restrict__ P,
    float* __restrict__ out, int n, int span) {
    const int j = blockIdx.x * TPB + threadIdx.x;
    const float Rj = Rarr[j];                       // lane-varying, coalesced
    if (j == 0 && blockIdx.y == 0) out[0] = 0.0f;   // harness poisons d_out
    const int ibase = blockIdx.y * span;

    float a0 = 0.0f, a1 = 0.0f, b0 = 0.0f, b1 = 0.0f;
    const int nch = span >> 4;                      // 16 i's per chunk
#pragma unroll 1
    for (int c = 0; c < nch; ++c) {
        const int base = ibase + (c << 4);
#pragma unroll
        for (int kk = 0; kk < 8; ++kk) {
            // wave-uniform loads -> SGPRs (s_load), K$-resident (64 KB total)
            const float r0 = Rarr[base + 2 * kk];
            const float r1 = Rarr[base + 2 * kk + 1];
            const float d0 = Darr[base + 2 * kk];
            const float d1 = Darr[base + 2 * kk + 1];
            const float l0 = Larr[base + 2 * kk];
            const float l1 = Larr[base + 2 * kk + 1];
            const float dr0 = r0 - Rj;
            const float dr1 = r1 - Rj;
            const float e0 = __builtin_amdgcn_exp2f(-(dr0 * dr0));  // exp(-drt^2/2)
            const float e1 = __builtin_amdgcn_exp2f(-(dr1 * dr1));
            const float t0 = __builtin_amdgcn_rcpf(fmaf(0.3916993f, fabsf(dr0), 1.0f));
            const float t1 = __builtin_amdgcn_rcpf(fmaf(0.3916993f, fabsf(dr1), 1.0f));
            const float u0 = t0 * fmaf(t0, fmaf(t0, 0.3739278f, -0.0479399f), 0.1740121f) * e0;
            const float u1 = t1 * fmaf(t1, fmaf(t1, 0.3739278f, -0.0479399f), 0.1740121f) * e1;
            a0 = fmaf(d0, e0, a0);
            a1 = fmaf(d1, e1, a1);
            // sign(dr)*(0.5-u), applied by XOR on the sign bit (exact)
            const float s0 = __uint_as_float(__float_as_uint(0.5f - u0)
                                             ^ (__float_as_uint(dr0) & 0x80000000u));
            const float s1 = __uint_as_float(__float_as_uint(0.5f - u1)
                                             ^ (__float_as_uint(dr1) & 0x80000000u));
            b0 = fmaf(l0, s0, b0);
            b1 = fmaf(l1, s1, b1);
        }
    }
    P[(size_t)blockIdx.y * n + j] = make_float2(a0 + a1, b0 + b1);
}

// out = (1/n) * sum_j d_j * (R_j - g2_j - log(c1*A_j + eps)
//                            + log(invn*(B_j + 0.5*sumL) + eps))
__global__ __launch_bounds__(TPB) void finalize_kernel(
    const float2* __restrict__ P, const float* __restrict__ m_z,
    const float* __restrict__ y, const float* __restrict__ delta,
    const float* __restrict__ LP, float* __restrict__ out,
    float c1, float invn, int n, int nlp) {
    const int j = blockIdx.x * TPB + threadIdx.x;
    float sa = 0.0f, sb = 0.0f;
    for (int b = 0; b < IB; ++b) {               // coalesced float2 reads
        const float2 v = P[(size_t)b * n + j];
        sa += v.x;
        sb += v.y;
    }
    float sumL = 0.0f;
    for (int w = 0; w < nlp; ++w) sumL += LP[w]; // uniform, K$-cached
    const float d = delta[j];
    const float R = m_z[2 * j] + __logf(y[j]);
    float term = d * (R - m_z[2 * j + 1] - __logf(fmaf(c1, sa, EPSF))
                      + __logf(fmaf(invn, sb + 0.5f * sumL, EPSF)));
    for (int o = 32; o > 0; o >>= 1) term += __shfl_down(term, o, 64);
    __shared__ float wsum[TPB / 64];
    if ((threadIdx.x & 63) == 0) wsum[threadIdx.x >> 6] = term;
    __syncthreads();
    if (threadIdx.x == 0) {
        float ssum = 0.0f;
        for (int w = 0; w < TPB / 64; ++w) ssum += wsum[w];
        atomicAdd(out, ssum * invn);
    }
}

extern "C" void kernel_launch(void* const* d_in, const int* in_sizes, int n_in,
                              void* d_out, int out_size, void* d_ws, size_t ws_size,
                              hipStream_t stream) {
    const float* m_z   = (const float*)d_in[0];   // (n,2)
    const float* y     = (const float*)d_in[1];   // (n,1)
    const float* delta = (const float*)d_in[2];   // (n,1)
    float* out = (float*)d_out;
    const int n = in_sizes[1];                    // 8192

    char* ws = (char*)d_ws;
    float2* P   = (float2*)ws;                    // IB * n * 8 B = 4 MB
    float* Rarr = (float*)(ws + 4194304);         // n floats
    float* Darr = Rarr + n;
    float* Larr = Darr + n;
    float* LP   = Larr + n;                       // nblk floats

    const double h = 1.3 * pow((double)n, -0.2);
    const double k = 1.1774100225154747;          // sqrt(2 ln 2)
    const float inv_hk = (float)(1.0 / (h * k));
    const float c1 = (float)(0.3989422804014327 / ((double)n * h)); // INV_SQRT_2PI/(n*h)
    const float invn = 1.0f / (float)n;
    const int span = n / IB;                      // 128

    const int nblk = (n + TPB - 1) / TPB;         // 32
    prep_kernel<<<nblk, TPB, 0, stream>>>(m_z, y, delta, Rarr, Darr, Larr, LP, inv_hk);

    dim3 grid(nblk, IB);                          // 2048 blocks = 8/CU
    pair_kernel<<<grid, TPB, 0, stream>>>(Rarr, Darr, Larr, P, out, n, span);

    finalize_kernel<<<nblk, TPB, 0, stream>>>(P, m_z, y, delta, LP, out, c1, invn, n, nblk);
}

// Round 5
// 83.868 us; speedup vs baseline: 1.0787x; 1.0787x over previous
//
#include <hip/hip_runtime.h>
#include <math.h>

#define TPB 256
#define IB 64
#define EPSF 1e-15f

typedef float f2 __attribute__((ext_vector_type(2)));

// Fused prep + O(n^2) pair kernel (2-kernel structure: R2/R4 showed each extra
// launch costs ~3-5us in this harness). Identical structure/grid/LDS to the
// proven 82.5us kernel; only the inner loop is rewritten on float2 vectors so
// the backend can emit packed v_pk_fma_f32/v_pk_mul_f32 (VOP3P, 2 f32/instr):
// ~24 -> ~14 VALU instructions per k-iter. Trans ops stay scalar; one rcp per
// k-iter is saved by a 2-way batched reciprocal (1/(nx*ny) trick, short chain).
//
// Math: Rs = (g1+log y)/(h*sqrt(2 ln 2)) so exp(-0.5*((R_i-R_j)/h)^2)=exp2(-dr^2).
// A_j = sum_i d_i*e;  L*Phi = 0.5*L + copysign(L,dr)*(0.5-u),
// u = upper-tail Q(|dr_true|) via A&S 7.1.25 3-term erfc (|eps|<=2.5e-5),
// reusing the SAME exp2; (0.5-u) computed as fma(-t*poly, e, 0.5).
// The 0.5*sum(L) over this block's span is folded into b-init once
// (spans partition i, so the block sum telescopes to 0.5*sum_all L).
__global__ __launch_bounds__(TPB, 8) void pair_kernel(
    const float* __restrict__ m_z, const float* __restrict__ y,
    const float* __restrict__ delta, float2* __restrict__ P,
    float* __restrict__ out, float inv_hk, int n, int span) {
    __shared__ float4 sRd[64];    // {R_2k, R_2k+1, d_2k, d_2k+1}
    __shared__ float2 sL2[64];    // {L_2k, L_2k+1}
    __shared__ float sLtot;
    const int tid = threadIdx.x;
    const int j = blockIdx.x * TPB + tid;
    const float2* __restrict__ mz2 = (const float2*)m_z;

    const float2 gj = mz2[j];
    const float Rj = (gj.x + __logf(y[j])) * inv_hk;

    // prep this block's i-span into LDS (span == 128)
    const int ibase = blockIdx.y * span;
    if (tid < span) {
        const int i = ibase + tid;
        const float2 g = mz2[i];
        float* s = (float*)sRd;
        const int pk = tid >> 1, hf = tid & 1;
        s[4 * pk + hf]     = (g.x + __logf(y[i])) * inv_hk;
        s[4 * pk + 2 + hf] = delta[i];
        ((float*)sL2)[tid] = __expf(g.y - g.x);
    }
    __syncthreads();
    if (tid < 64) {  // wave 0: sum L over the span
        float s = 0.0f;
        for (int t = tid; t < span; t += 64) s += ((float*)sL2)[t];
        for (int o = 32; o > 0; o >>= 1) s += __shfl_down(s, o, 64);
        if (tid == 0) sLtot = s;
    }
    __syncthreads();
    if (j == 0 && blockIdx.y == 0) out[0] = 0.0f;  // harness poisons d_out

    const f2 Rj2   = {Rj, Rj};
    const f2 p2    = {0.3916993f, 0.3916993f};
    const f2 one2  = {1.0f, 1.0f};
    const f2 half2 = {0.5f, 0.5f};
    const f2 k3    = {0.3739278f, 0.3739278f};
    const f2 k2    = {-0.0479399f, -0.0479399f};
    const f2 k1    = {0.1740121f, 0.1740121f};
    f2 aa = {0.0f, 0.0f};
    f2 bb = {0.5f * sLtot, 0.0f};
    const int m = span >> 1;                      // 64 k-iters, 2 pairs each
#pragma unroll 4
    for (int k = 0; k < m; ++k) {
        const float4 rd = sRd[k];                 // broadcast LDS reads
        const float2 ll = sL2[k];
        const f2 Rv = {rd.x, rd.y};
        const f2 Dv = {rd.z, rd.w};
        const f2 dr = Rv - Rj2;                   // v_pk_add (neg mod)
        const f2 mm = dr * dr;                    // v_pk_mul
        f2 e;                                     // exp(-drt^2/2) = exp2(-dr^2)
        e.x = __builtin_amdgcn_exp2f(-mm.x);
        e.y = __builtin_amdgcn_exp2f(-mm.y);
        const f2 nn = __builtin_elementwise_fma(p2, __builtin_elementwise_abs(dr), one2);
        const float rr = __builtin_amdgcn_rcpf(nn.x * nn.y);  // batched rcp
        f2 t;
        t.x = rr * nn.y;                          // 1/nn.x
        t.y = rr * nn.x;                          // 1/nn.y
        f2 q = __builtin_elementwise_fma(t, k3, k2);
        q    = __builtin_elementwise_fma(t, q, k1);
        const f2 v = t * q;                       // u = v*e
        const f2 h = __builtin_elementwise_fma(-v, e, half2);  // 0.5 - u
        aa = __builtin_elementwise_fma(Dv, e, aa);
        f2 s;
        s.x = copysignf(ll.x, dr.x);
        s.y = copysignf(ll.y, dr.y);
        bb = __builtin_elementwise_fma(s, h, bb);
    }
    P[(size_t)blockIdx.y * n + j] = make_float2(aa.x + aa.y, bb.x + bb.y);
}

// out = (1/n) * sum_j d_j * (R_j - g2_j - log(c1*A_j + eps) + log(invn*B_j + eps))
__global__ __launch_bounds__(TPB) void finalize_kernel(
    const float2* __restrict__ P, const float* __restrict__ m_z,
    const float* __restrict__ y, const float* __restrict__ delta,
    float* __restrict__ out, float c1, float invn, int n) {
    const int j = blockIdx.x * TPB + threadIdx.x;
    float sa = 0.0f, sb = 0.0f;
    for (int b = 0; b < IB; ++b) {               // coalesced float2 reads
        const float2 v = P[(size_t)b * n + j];
        sa += v.x;
        sb += v.y;
    }
    const float d = delta[j];
    const float R = m_z[2 * j] + __logf(y[j]);
    float term = d * (R - m_z[2 * j + 1] - __logf(fmaf(c1, sa, EPSF))
                                         + __logf(fmaf(invn, sb, EPSF)));
    for (int o = 32; o > 0; o >>= 1) term += __shfl_down(term, o, 64);
    __shared__ float wsum[TPB / 64];
    if ((threadIdx.x & 63) == 0) wsum[threadIdx.x >> 6] = term;
    __syncthreads();
    if (threadIdx.x == 0) {
        float ssum = 0.0f;
        for (int w = 0; w < TPB / 64; ++w) ssum += wsum[w];
        atomicAdd(out, ssum * invn);
    }
}

extern "C" void kernel_launch(void* const* d_in, const int* in_sizes, int n_in,
                              void* d_out, int out_size, void* d_ws, size_t ws_size,
                              hipStream_t stream) {
    const float* m_z   = (const float*)d_in[0];   // (n,2)
    const float* y     = (const float*)d_in[1];   // (n,1)
    const float* delta = (const float*)d_in[2];   // (n,1)
    float* out = (float*)d_out;
    const int n = in_sizes[1];                    // 8192

    float2* P = (float2*)d_ws;                    // IB * n * 8 B = 4 MB

    const double h = 1.3 * pow((double)n, -0.2);
    const double k = 1.1774100225154747;          // sqrt(2 ln 2)
    const float inv_hk = (float)(1.0 / (h * k));
    const float c1 = (float)(0.3989422804014327 / ((double)n * h)); // INV_SQRT_2PI/(n*h)
    const float invn = 1.0f / (float)n;
    const int span = n / IB;                      // 128

    const int nblk = (n + TPB - 1) / TPB;         // 32
    dim3 grid(nblk, IB);                          // 2048 blocks = 8/CU
    pair_kernel<<<grid, TPB, 0, stream>>>(m_z, y, delta, P, out, inv_hk, n, span);
    finalize_kernel<<<nblk, TPB, 0, stream>>>(P, m_z, y, delta, out, c1, invn, n);
}